// Round 4
// baseline (450.273 us; speedup 1.0000x reference)
//
#include <hip/hip_runtime.h>
#include <cstdint>
#include <cstddef>

#define NN 64
#define CC 192
#define VV 25
#define TTT 300
#define TB 3
#define NTB 100         // 300/3
#define GRID (NN*NTB)   // 6400
#define WMEXT_OFF 36864 // u16 elements into ws: 16x192 block, row0 = wm

// --- fast path (precomputed Xb slabs, 400B padded rows) ---
#define ROWP 400               // padded row bytes (25 x 16B; odd 16B-slot stride)
#define SLAB 30000             // 75 rows x 400B
#define XB_OFF 131072          // byte offset of Xb in ws
#define XB_BYTES (6400LL*SLAB) // 192,000,000
#define F_XT_OFF 0
#define F_YT_OFF 30000
#define F_SIM_OFF 68400
#define F_MSK_OFF 76800
#define F_RS_OFF 77136
#define F_CS_OFF 77472
#define F_LDS_BYTES 77824      // <= 81920 -> 2 blocks/CU

// --- fallback path (round-3, direct x1 staging, 384B swizzled rows) ---
#define ROWB 384
#define D_XT_OFF 0
#define D_YT_OFF 31488
#define D_SIM_OFF 68352
#define D_MSK_OFF 76752
#define D_RS_OFF 77088
#define D_CS_OFF 77424
#define D_LDS_BYTES 77760

typedef unsigned short u16;
typedef short bf16x8 __attribute__((ext_vector_type(8)));
typedef float f32x4 __attribute__((ext_vector_type(4)));
typedef int i32x4 __attribute__((ext_vector_type(4)));

__device__ __forceinline__ u16 f2bf(float x) {
  union { float f; uint32_t u; } v; v.f = x;
  uint32_t r = v.u + 0x7fffu + ((v.u >> 16) & 1u);
  return (u16)(r >> 16);
}
__device__ __forceinline__ int swz(int row, int colb) {
  return row * ROWB + (colb ^ ((row & 7) << 4));
}

// blocks 0..191: M[c1][c2] = sum_d w1[d][c1]*w2[d][c2] (bf16).
// block 192: wmext 16x192 (row0 = wm bf16, rows 1..15 = 0).
__global__ __launch_bounds__(192) void prep(const float* __restrict__ w1,
                                            const float* __restrict__ w2,
                                            const float* __restrict__ wm,
                                            u16* __restrict__ mb) {
  int c2 = threadIdx.x;
  int b = blockIdx.x;
  if (b < CC) {
    float s = 0.f;
    for (int d = 0; d < CC; ++d) s += w1[d * CC + b] * w2[d * CC + c2];
    mb[b * CC + c2] = f2bf(s);
  } else {
    mb[WMEXT_OFF + c2] = f2bf(wm[c2]);
    #pragma unroll
    for (int r = 1; r < 16; ++r) mb[WMEXT_OFF + r * CC + c2] = 0;
  }
}

// K0: transpose/convert x1 [n][c][v][t] f32 -> Xb slabs [n*100+t/3][(t%3)*25+v][c] bf16,
// 400B padded rows. Reads fully coalesced along t; 8B writes row-assembled in L2.
__global__ __launch_bounds__(512) void k0(const float* __restrict__ x1,
                                          char* __restrict__ xb) {
  int n = blockIdx.x / 5, tr = blockIdx.x - (blockIdx.x / 5) * 5;
  int t0 = tr * 64;
  int wid = threadIdx.x >> 6, lane = threadIdx.x & 63;
  int tsub = lane & 15;     // 16 consecutive t per c-subgroup
  int csub = lane >> 4;     // 4 c-subgroups x 4 c
  // pair p = v*4 + strip; each wave owns p == wid (mod 8) and loops all c:
  for (int p = wid; p < 100; p += 8) {
    int v = p >> 2, strip = p & 3;
    int t = t0 + strip * 16 + tsub;
    bool ok = t < TTT;
    int s = t / 3, tt = t - 3 * s;
    size_t rb = (size_t)(n * NTB + s) * SLAB + (size_t)(tt * VV + v) * ROWP;
    const float* src = x1 + ((size_t)(n * CC) * VV + v) * TTT + t;
    for (int cg = 0; cg < 12; ++cg) {
      int c0 = cg * 16 + csub * 4;
      if (ok) {
        float f0 = src[(size_t)(c0 + 0) * (VV * TTT)];
        float f1 = src[(size_t)(c0 + 1) * (VV * TTT)];
        float f2 = src[(size_t)(c0 + 2) * (VV * TTT)];
        float f3 = src[(size_t)(c0 + 3) * (VV * TTT)];
        uint64_t pk = (uint64_t)f2bf(f0) | ((uint64_t)f2bf(f1) << 16) |
                      ((uint64_t)f2bf(f2) << 32) | ((uint64_t)f2bf(f3) << 48);
        *(uint64_t*)(xb + rb + c0 * 2) = pk;
      }
    }
  }
}

// K2 fast: one block = (n, 3 t's). Stage slab linearly; pass1 Y=M@X; pass2 sim+mask;
// stats-based centering; softmax; store.
__global__ __launch_bounds__(512, 4) void fused_fast(const char* __restrict__ xb,
                                                     const u16* __restrict__ mb,
                                                     float* __restrict__ out) {
  extern __shared__ char lds[];
  char* XT = lds + F_XT_OFF;
  char* YT = lds + F_YT_OFF;
  float* SIM = (float*)(lds + F_SIM_OFF);
  float* MSK = (float*)(lds + F_MSK_OFF);
  float* RS = (float*)(lds + F_RS_OFF);
  float* CS = (float*)(lds + F_CS_OFF);

  const int tid = threadIdx.x;
  const int wid = tid >> 6;
  const int lane = tid & 63;
  const int lr = lane & 15;
  const int lq = lane >> 4;

  int b = blockIdx.x;
  int logical = (b & 7) * (GRID / 8) + (b >> 3);
  int n = logical / NTB;
  int tb = logical - n * NTB;
  int t0 = tb * TB;

  // ---- stage: linear 16B copies of the precomputed slab image ----
  const char* sg = xb + (size_t)(n * NTB + tb) * SLAB;
  for (int i = tid; i < SLAB / 16; i += 512)
    *(i32x4*)(XT + i * 16) = *(const i32x4*)(sg + i * 16);
  __syncthreads();

  // ---- pass1: Y = M @ X  (M=192 x N=96 x K=192); 8 waves = 4 mg x 2 ng ----
  const int mg = wid >> 1;
  const int ng = wid & 1;
  f32x4 acc[3][3];
  #pragma unroll
  for (int mt = 0; mt < 3; ++mt)
    #pragma unroll
    for (int nt = 0; nt < 3; ++nt) acc[mt][nt] = (f32x4){0.f, 0.f, 0.f, 0.f};

  #pragma unroll
  for (int ks = 0; ks < 6; ++ks) {
    bf16x8 bfr[3];
    #pragma unroll
    for (int nt = 0; nt < 3; ++nt) {
      int j = ng * 48 + nt * 16 + lr;
      bfr[nt] = *(const bf16x8*)(XT + j * ROWP + ks * 64 + lq * 16);
    }
    #pragma unroll
    for (int mt = 0; mt < 3; ++mt) {
      int c1 = mg * 48 + mt * 16 + lr;
      bf16x8 a = *(const bf16x8*)(mb + c1 * CC + ks * 32 + lq * 8);
      #pragma unroll
      for (int nt = 0; nt < 3; ++nt)
        acc[mt][nt] = __builtin_amdgcn_mfma_f32_16x16x32_bf16(a, bfr[nt], acc[mt][nt], 0, 0, 0);
    }
  }
  #pragma unroll
  for (int mt = 0; mt < 3; ++mt) {
    #pragma unroll
    for (int nt = 0; nt < 3; ++nt) {
      int j = ng * 48 + nt * 16 + lr;
      int c1b = (mg * 48 + mt * 16 + lq * 4) * 2;
      f32x4 a = acc[mt][nt];
      uint64_t pk = (uint64_t)f2bf(a[0]) | ((uint64_t)f2bf(a[1]) << 16) |
                    ((uint64_t)f2bf(a[2]) << 32) | ((uint64_t)f2bf(a[3]) << 48);
      *(uint64_t*)(YT + j * ROWP + c1b) = pk;
    }
  }
  __syncthreads();

  // ---- pass2: 12 sim jobs + 6 mask jobs ----
  for (int job = wid; job < 18; job += 8) {
    if (job < 12) {
      int tt = job >> 2, vt = (job >> 1) & 1, wt = job & 1;
      int ar = tt * VV + vt * 16 + lr;
      int br = tt * VV + wt * 16 + lr;
      f32x4 s = (f32x4){0.f, 0.f, 0.f, 0.f};
      #pragma unroll
      for (int ks = 0; ks < 6; ++ks) {
        bf16x8 a = *(const bf16x8*)(XT + ar * ROWP + ks * 64 + lq * 16);
        bf16x8 bb = *(const bf16x8*)(YT + br * ROWP + ks * 64 + lq * 16);
        s = __builtin_amdgcn_mfma_f32_16x16x32_bf16(a, bb, s, 0, 0, 0);
      }
      int w = wt * 16 + lr;
      if (w < VV) {
        #pragma unroll
        for (int i = 0; i < 4; ++i) {
          int v = vt * 16 + lq * 4 + i;
          if (v < VV) SIM[(tt * VV + v) * 28 + w] = s[i];
        }
      }
    } else {
      int m = job - 12;
      int tt = m >> 1, wt = m & 1;
      int br = tt * VV + wt * 16 + lr;
      f32x4 s = (f32x4){0.f, 0.f, 0.f, 0.f};
      #pragma unroll
      for (int ks = 0; ks < 6; ++ks) {
        bf16x8 a = *(const bf16x8*)(mb + WMEXT_OFF + lr * CC + ks * 32 + lq * 8);
        bf16x8 bb = *(const bf16x8*)(XT + br * ROWP + ks * 64 + lq * 16);
        s = __builtin_amdgcn_mfma_f32_16x16x32_bf16(a, bb, s, 0, 0, 0);
      }
      int w = wt * 16 + lr;
      if (lq == 0 && w < VV) MSK[tt * 28 + w] = s[0];
    }
  }
  __syncthreads();

  // ---- stats: row / col sums of each 25x25 sim ----
  if (tid < 150) {
    int q = tid / 25, idx = tid - q * 25;
    int tt = q >> 1;
    const float* sb = SIM + tt * VV * 28;
    float s = 0.f;
    if (q & 1) {
      #pragma unroll
      for (int w = 0; w < VV; ++w) s += sb[idx * 28 + w];
      RS[tt * 28 + idx] = s;
    } else {
      #pragma unroll
      for (int v = 0; v < VV; ++v) s += sb[v * 28 + idx];
      CS[tt * 28 + idx] = s;
    }
  }
  __syncthreads();

  // ---- centering + mask + softmax + store ----
  if (tid < TB * VV) {
    int tt = tid / VV, v = tid - tt * VV;
    const float* sb = SIM + (tt * VV + v) * 28;
    const float* cs = CS + tt * 28;
    float tot = 0.f;
    #pragma unroll
    for (int w = 0; w < VV; ++w) tot += cs[w];
    const float base = -RS[tt * 28 + v] * 0.04f + tot * 0.0016f;
    const float isc = 0.07216878364870323f;
    float l[VV];
    float mx = -1e30f;
    #pragma unroll
    for (int w = 0; w < VV; ++w) {
      float val = (sb[w] - cs[w] * 0.04f + base) * isc + MSK[tt * 28 + w];
      l[w] = val;
      mx = fmaxf(mx, val);
    }
    float sum = 0.f;
    #pragma unroll
    for (int w = 0; w < VV; ++w) { float e = __expf(l[w] - mx); l[w] = e; sum += e; }
    float rs = 1.0f / sum;
    float* o = out + (((size_t)n * TTT + t0 + tt) * VV + v) * VV;
    #pragma unroll
    for (int w = 0; w < VV; ++w) o[w] = l[w] * rs;
  }
}

// ---- fallback: round-3 fused (direct x1 staging) verbatim ----
__global__ __launch_bounds__(512, 4) void fused_direct(const float* __restrict__ x1,
                                                       const u16* __restrict__ mb,
                                                       float* __restrict__ out) {
  extern __shared__ char lds[];
  char* XT = lds + D_XT_OFF;
  char* YT = lds + D_YT_OFF;
  float* SIM = (float*)(lds + D_SIM_OFF);
  float* MSK = (float*)(lds + D_MSK_OFF);
  float* RS = (float*)(lds + D_RS_OFF);
  float* CS = (float*)(lds + D_CS_OFF);

  const int tid = threadIdx.x;
  const int wid = tid >> 6;
  const int lane = tid & 63;
  const int lr = lane & 15;
  const int lq = lane >> 4;

  int b = blockIdx.x;
  int logical = (b & 7) * (GRID / 8) + (b >> 3);
  int n = logical / NTB;
  int tb = logical - n * NTB;
  int t0 = tb * TB;

  const float* xb = x1 + (size_t)n * (CC * VV * TTT) + t0;
  for (int job = tid; job < 1200; job += 512) {
    int cq = job / 25, v = job - cq * 25;
    const float* p = xb + (cq * 4 * VV + v) * TTT;
    float a[4][TB];
    #pragma unroll
    for (int i = 0; i < 4; ++i) {
      const float* q = p + i * VV * TTT;
      a[i][0] = q[0]; a[i][1] = q[1]; a[i][2] = q[2];
    }
    #pragma unroll
    for (int tt = 0; tt < TB; ++tt) {
      uint64_t pk = (uint64_t)f2bf(a[0][tt]) | ((uint64_t)f2bf(a[1][tt]) << 16) |
                    ((uint64_t)f2bf(a[2][tt]) << 32) | ((uint64_t)f2bf(a[3][tt]) << 48);
      *(uint64_t*)(XT + swz(tt * 25 + v, cq * 8)) = pk;
    }
  }
  __syncthreads();

  const int mg = wid >> 1;
  const int ng = wid & 1;
  f32x4 acc[3][3];
  #pragma unroll
  for (int mt = 0; mt < 3; ++mt)
    #pragma unroll
    for (int nt = 0; nt < 3; ++nt) acc[mt][nt] = (f32x4){0.f, 0.f, 0.f, 0.f};

  #pragma unroll
  for (int ks = 0; ks < 6; ++ks) {
    bf16x8 bfr[3];
    #pragma unroll
    for (int nt = 0; nt < 3; ++nt) {
      int j = ng * 48 + nt * 16 + lr;
      bfr[nt] = *(const bf16x8*)(XT + swz(j, ks * 64 + lq * 16));
    }
    #pragma unroll
    for (int mt = 0; mt < 3; ++mt) {
      int c1 = mg * 48 + mt * 16 + lr;
      bf16x8 a = *(const bf16x8*)(mb + c1 * CC + ks * 32 + lq * 8);
      #pragma unroll
      for (int nt = 0; nt < 3; ++nt)
        acc[mt][nt] = __builtin_amdgcn_mfma_f32_16x16x32_bf16(a, bfr[nt], acc[mt][nt], 0, 0, 0);
    }
  }
  #pragma unroll
  for (int mt = 0; mt < 3; ++mt) {
    #pragma unroll
    for (int nt = 0; nt < 3; ++nt) {
      int j = ng * 48 + nt * 16 + lr;
      int c1b = (mg * 48 + mt * 16 + lq * 4) * 2;
      f32x4 a = acc[mt][nt];
      uint64_t pk = (uint64_t)f2bf(a[0]) | ((uint64_t)f2bf(a[1]) << 16) |
                    ((uint64_t)f2bf(a[2]) << 32) | ((uint64_t)f2bf(a[3]) << 48);
      *(uint64_t*)(YT + swz(j, c1b)) = pk;
    }
  }
  __syncthreads();

  for (int job = wid; job < 18; job += 8) {
    if (job < 12) {
      int tt = job >> 2, vt = (job >> 1) & 1, wt = job & 1;
      int ar = tt * 25 + vt * 16 + lr;
      int br = tt * 25 + wt * 16 + lr;
      f32x4 s = (f32x4){0.f, 0.f, 0.f, 0.f};
      #pragma unroll
      for (int ks = 0; ks < 6; ++ks) {
        bf16x8 a = *(const bf16x8*)(XT + swz(ar, ks * 64 + lq * 16));
        bf16x8 bb = *(const bf16x8*)(YT + swz(br, ks * 64 + lq * 16));
        s = __builtin_amdgcn_mfma_f32_16x16x32_bf16(a, bb, s, 0, 0, 0);
      }
      int w = wt * 16 + lr;
      if (w < VV) {
        #pragma unroll
        for (int i = 0; i < 4; ++i) {
          int v = vt * 16 + lq * 4 + i;
          if (v < VV) SIM[(tt * VV + v) * 28 + w] = s[i];
        }
      }
    } else {
      int m = job - 12;
      int tt = m >> 1, wt = m & 1;
      int br = tt * 25 + wt * 16 + lr;
      f32x4 s = (f32x4){0.f, 0.f, 0.f, 0.f};
      #pragma unroll
      for (int ks = 0; ks < 6; ++ks) {
        bf16x8 a = *(const bf16x8*)(mb + WMEXT_OFF + lr * CC + ks * 32 + lq * 8);
        bf16x8 bb = *(const bf16x8*)(XT + swz(br, ks * 64 + lq * 16));
        s = __builtin_amdgcn_mfma_f32_16x16x32_bf16(a, bb, s, 0, 0, 0);
      }
      int w = wt * 16 + lr;
      if (lq == 0 && w < VV) MSK[tt * 28 + w] = s[0];
    }
  }
  __syncthreads();

  if (tid < 150) {
    int q = tid / 25, idx = tid - q * 25;
    int tt = q >> 1;
    const float* sb = SIM + tt * VV * 28;
    float s = 0.f;
    if (q & 1) {
      #pragma unroll
      for (int w = 0; w < VV; ++w) s += sb[idx * 28 + w];
      RS[tt * 28 + idx] = s;
    } else {
      #pragma unroll
      for (int v = 0; v < VV; ++v) s += sb[v * 28 + idx];
      CS[tt * 28 + idx] = s;
    }
  }
  __syncthreads();

  if (tid < TB * VV) {
    int tt = tid / VV, v = tid - tt * VV;
    const float* sb = SIM + (tt * VV + v) * 28;
    const float* cs = CS + tt * 28;
    float tot = 0.f;
    #pragma unroll
    for (int w = 0; w < VV; ++w) tot += cs[w];
    const float base = -RS[tt * 28 + v] * 0.04f + tot * 0.0016f;
    const float isc = 0.07216878364870323f;
    float l[VV];
    float mx = -1e30f;
    #pragma unroll
    for (int w = 0; w < VV; ++w) {
      float val = (sb[w] - cs[w] * 0.04f + base) * isc + MSK[tt * 28 + w];
      l[w] = val;
      mx = fmaxf(mx, val);
    }
    float sum = 0.f;
    #pragma unroll
    for (int w = 0; w < VV; ++w) { float e = __expf(l[w] - mx); l[w] = e; sum += e; }
    float rs = 1.0f / sum;
    float* o = out + (((size_t)n * TTT + t0 + tt) * VV + v) * VV;
    #pragma unroll
    for (int w = 0; w < VV; ++w) o[w] = l[w] * rs;
  }
}

extern "C" void kernel_launch(void* const* d_in, const int* in_sizes, int n_in,
                              void* d_out, int out_size, void* d_ws, size_t ws_size,
                              hipStream_t stream) {
  const float* x1 = (const float*)d_in[0];
  const float* w1 = (const float*)d_in[1];
  const float* w2 = (const float*)d_in[2];
  const float* wm = (const float*)d_in[3];
  float* out = (float*)d_out;
  u16* mb = (u16*)d_ws;

  hipLaunchKernelGGL(prep, dim3(CC + 1), dim3(CC), 0, stream, w1, w2, wm, mb);
  if (ws_size >= (size_t)XB_OFF + (size_t)XB_BYTES) {
    char* xb = (char*)d_ws + XB_OFF;
    hipLaunchKernelGGL(k0, dim3(NN * 5), dim3(512), 0, stream, x1, xb);
    hipLaunchKernelGGL(fused_fast, dim3(GRID), dim3(512), F_LDS_BYTES, stream, xb, mb, out);
  } else {
    hipLaunchKernelGGL(fused_direct, dim3(GRID), dim3(512), D_LDS_BYTES, stream, x1, mb, out);
  }
}

// Round 5
// 308.219 us; speedup vs baseline: 1.4609x; 1.4609x over previous
//
#include <hip/hip_runtime.h>
#include <cstdint>
#include <cstddef>

#define NN 64
#define CC 192
#define VV 25
#define TTT 300
#define TCH 12          // t per block
#define NCH 25          // 300/12
#define GRID (NN*NCH)   // 1600
#define COLS 300        // TCH*VV, col = tt*25 + v
#define ROWB 384        // X row bytes (192 c * 2B), XOR-swizzled
#define YROWB 80        // Y row bytes (32 c1 * 2B + 16B pad -> conflict-free)
// LDS layout (bytes)
#define X_OFF 0         // 300(+6 overread) rows x 384B = 115,200
#define Y_OFF 115200    // 308 rows x 80B = 24,640
#define LDS_BYTES 139840
// epilogue aliases into dead X region
#define SIM_OFF 0       // [300][28] f32 = 33,600
#define RS_OFF 33600    // [12][28] f32
#define CS_OFF 34944    // [12][28] f32
#define MSK_OFF 36288   // [304] f32
// ws layout (u16 units): M [192][192] then wm bf16[192]
#define WMB_OFF 36864

typedef unsigned short u16;
typedef unsigned long long u64;
typedef short bf16x8 __attribute__((ext_vector_type(8)));
typedef float f32x4 __attribute__((ext_vector_type(4)));
typedef float f4 __attribute__((ext_vector_type(4)));
typedef u64 u64x2 __attribute__((ext_vector_type(2)));

__device__ __forceinline__ u16 f2bf(float x) {
  union { float f; uint32_t u; } v; v.f = x;
  uint32_t r = v.u + 0x7fffu + ((v.u >> 16) & 1u);
  return (u16)(r >> 16);
}
__device__ __forceinline__ u64 pack4(f32x4 a) {
  return (u64)f2bf(a[0]) | ((u64)f2bf(a[1]) << 16) |
         ((u64)f2bf(a[2]) << 32) | ((u64)f2bf(a[3]) << 48);
}
// XOR swizzle on 384B rows: spreads 16B slots by row (kills stride≡0 mod 128 conflicts)
__device__ __forceinline__ int swz(int row, int colb) {
  return row * ROWB + (colb ^ ((row & 7) << 4));
}

// blocks 0..191: M[c1][c2] = sum_d w1[d][c1]*w2[d][c2] (bf16). block 192: wm -> bf16.
__global__ __launch_bounds__(192) void prep(const float* __restrict__ w1,
                                            const float* __restrict__ w2,
                                            const float* __restrict__ wm,
                                            u16* __restrict__ mb) {
  int c2 = threadIdx.x;
  int b = blockIdx.x;
  if (b < CC) {
    float s = 0.f;
    for (int d = 0; d < CC; ++d) s += w1[d * CC + b] * w2[d * CC + c2];
    mb[b * CC + c2] = f2bf(s);
  } else {
    mb[WMB_OFF + c2] = f2bf(wm[c2]);
  }
}

// One block = (n, 12 consecutive t). Phases:
//   stage X (coalesced float4 over t) -> XT[col=(tt*25+v)][c] swizzled
//   6 x { pass1: Y-chunk[c1 32][col] = M-chunk @ X ; barrier ;
//         pass2: pacc += X^T Y-chunk (per t) + mask acc ; barrier }
//   epilogue: SIM/MSK from regs -> LDS, row/col stats, centering+softmax, store.
__global__ __launch_bounds__(512, 2) void fused(const float* __restrict__ x1,
                                                const u16* __restrict__ mb,
                                                float* __restrict__ out) {
  extern __shared__ char lds[];
  char* XT = lds + X_OFF;
  char* YT = lds + Y_OFF;
  float* SIM = (float*)(lds + SIM_OFF);
  float* RS = (float*)(lds + RS_OFF);
  float* CS = (float*)(lds + CS_OFF);
  float* MSKF = (float*)(lds + MSK_OFF);

  const int tid = threadIdx.x;
  const int wid = tid >> 6;
  const int lane = tid & 63;
  const int lr = lane & 15;
  const int lq = lane >> 4;

  // XCD-chunked bijective swizzle (GRID % 8 == 0)
  int b = blockIdx.x;
  int logical = (b & 7) * (GRID / 8) + (b >> 3);
  int n = logical / NCH;
  int tch = logical - n * NCH;
  int t0 = tch * TCH;

  // ---- stage: job = (c-octet, v, t-quad); 8 coalesced float4 loads, 4 b128 LDS writes ----
  const float* xb = x1 + (size_t)n * (CC * VV * TTT) + t0;
  for (int job = tid; job < 1800; job += 512) {
    int co = job / 75;
    int r = job - co * 75;
    int v = r / 3;
    int seg = r - v * 3;
    const float* p = xb + (size_t)(co * 8 * VV + v) * TTT + seg * 4;
    f4 a[8];
    #pragma unroll
    for (int i = 0; i < 8; ++i) a[i] = *(const f4*)(p + (size_t)i * (VV * TTT));
    #pragma unroll
    for (int dt = 0; dt < 4; ++dt) {
      int row = (seg * 4 + dt) * VV + v;
      u64 lo = (u64)f2bf(a[0][dt]) | ((u64)f2bf(a[1][dt]) << 16) |
               ((u64)f2bf(a[2][dt]) << 32) | ((u64)f2bf(a[3][dt]) << 48);
      u64 hi = (u64)f2bf(a[4][dt]) | ((u64)f2bf(a[5][dt]) << 16) |
               ((u64)f2bf(a[6][dt]) << 32) | ((u64)f2bf(a[7][dt]) << 48);
      *(u64x2*)(XT + swz(row, co * 16)) = (u64x2){lo, hi};
    }
  }

  f32x4 pacc[6], macc[3];
  #pragma unroll
  for (int i = 0; i < 6; ++i) pacc[i] = (f32x4){0.f, 0.f, 0.f, 0.f};
  #pragma unroll
  for (int i = 0; i < 3; ++i) macc[i] = (f32x4){0.f, 0.f, 0.f, 0.f};

  __syncthreads();

  // ---- chunk loop over c1 (6 chunks of 32) ----
  for (int cc = 0; cc < 6; ++cc) {
    // pass1: Y[col][c1-chunk] = M[c1-chunk,:] @ X ; 19 col-tiles over 8 waves
    for (int j = wid; j < 19; j += 8) {
      f32x4 acc0 = (f32x4){0.f, 0.f, 0.f, 0.f};
      f32x4 acc1 = (f32x4){0.f, 0.f, 0.f, 0.f};
      #pragma unroll
      for (int ks = 0; ks < 6; ++ks) {
        bf16x8 bb = *(const bf16x8*)(XT + swz(j * 16 + lr, ks * 64 + lq * 16));
        bf16x8 a0 = *(const bf16x8*)(mb + (cc * 32 + lr) * CC + ks * 32 + lq * 8);
        bf16x8 a1 = *(const bf16x8*)(mb + (cc * 32 + 16 + lr) * CC + ks * 32 + lq * 8);
        acc0 = __builtin_amdgcn_mfma_f32_16x16x32_bf16(a0, bb, acc0, 0, 0, 0);
        acc1 = __builtin_amdgcn_mfma_f32_16x16x32_bf16(a1, bb, acc1, 0, 0, 0);
      }
      int col = j * 16 + lr;
      *(u64*)(YT + col * YROWB + lq * 8) = pack4(acc0);
      *(u64*)(YT + col * YROWB + 32 + lq * 8) = pack4(acc1);
    }
    __syncthreads();

    // pass2: 48 jobs (tt,vt,wt), 6 fixed per wave; K-accumulate across chunks
    #pragma unroll
    for (int jj = 0; jj < 6; ++jj) {
      int job = wid * 6 + jj;
      int tt = job >> 2, vt = (job >> 1) & 1, wt = job & 1;
      bf16x8 a = *(const bf16x8*)(XT + swz(tt * VV + vt * 16 + lr, cc * 64 + lq * 16));
      bf16x8 bb = *(const bf16x8*)(YT + (tt * VV + wt * 16 + lr) * YROWB + lq * 16);
      pacc[jj] = __builtin_amdgcn_mfma_f32_16x16x32_bf16(a, bb, pacc[jj], 0, 0, 0);
    }
    // mask: mask[col] = sum_c wm[c]*X[c,col]; B = broadcast wm fragment
    bf16x8 wmf = *(const bf16x8*)(mb + WMB_OFF + cc * 32 + lq * 8);
    #pragma unroll
    for (int jm = 0; jm < 3; ++jm) {
      int j = wid + jm * 8;
      if (j < 19) {
        bf16x8 a = *(const bf16x8*)(XT + swz(j * 16 + lr, cc * 64 + lq * 16));
        macc[jm] = __builtin_amdgcn_mfma_f32_16x16x32_bf16(a, wmf, macc[jm], 0, 0, 0);
      }
    }
    __syncthreads();
  }

  // ---- spill acc -> LDS (X region dead after last barrier) ----
  #pragma unroll
  for (int jm = 0; jm < 3; ++jm) {
    int j = wid + jm * 8;
    if (j < 19 && lr == 0) {
      #pragma unroll
      for (int i = 0; i < 4; ++i) {
        int col = j * 16 + lq * 4 + i;
        if (col < COLS) MSKF[col] = macc[jm][i];
      }
    }
  }
  #pragma unroll
  for (int jj = 0; jj < 6; ++jj) {
    int job = wid * 6 + jj;
    int tt = job >> 2, vt = (job >> 1) & 1, wt = job & 1;
    int w = wt * 16 + lr;
    if (w < VV) {
      #pragma unroll
      for (int i = 0; i < 4; ++i) {
        int v = vt * 16 + lq * 4 + i;
        if (v < VV) SIM[(tt * VV + v) * 28 + w] = pacc[jj][i];
      }
    }
  }
  __syncthreads();

  // ---- stats: per tt, 25 row sums + 25 col sums ----
  for (int job = tid; job < 600; job += 512) {
    int tt = job / 50;
    int r = job - tt * 50;
    const float* sb = SIM + tt * VV * 28;
    float s = 0.f;
    if (r < VV) {
      #pragma unroll
      for (int w2 = 0; w2 < VV; ++w2) s += sb[r * 28 + w2];
      RS[tt * 28 + r] = s;
    } else {
      int w2 = r - VV;
      #pragma unroll
      for (int v2 = 0; v2 < VV; ++v2) s += sb[v2 * 28 + w2];
      CS[tt * 28 + w2] = s;
    }
  }
  __syncthreads();

  // ---- centering + mask + softmax + store ----
  if (tid < COLS) {
    int tt = tid / VV, v = tid - tt * VV;
    const float* sb = SIM + (tt * VV + v) * 28;
    const float* cs = CS + tt * 28;
    float tot = 0.f;
    #pragma unroll
    for (int w = 0; w < VV; ++w) tot += cs[w];
    const float base = -RS[tt * 28 + v] * 0.04f + tot * 0.0016f;
    const float isc = 0.07216878364870323f;  // 1/sqrt(192)
    float l[VV];
    float mx = -1e30f;
    #pragma unroll
    for (int w = 0; w < VV; ++w) {
      float val = (sb[w] - cs[w] * 0.04f + base) * isc + MSKF[tt * VV + w];
      l[w] = val;
      mx = fmaxf(mx, val);
    }
    float sum = 0.f;
    #pragma unroll
    for (int w = 0; w < VV; ++w) { float e = __expf(l[w] - mx); l[w] = e; sum += e; }
    float rsc = 1.0f / sum;
    float* o = out + (((size_t)n * TTT + t0 + tt) * VV + v) * VV;
    #pragma unroll
    for (int w = 0; w < VV; ++w) o[w] = l[w] * rsc;
  }
}

extern "C" void kernel_launch(void* const* d_in, const int* in_sizes, int n_in,
                              void* d_out, int out_size, void* d_ws, size_t ws_size,
                              hipStream_t stream) {
  const float* x1 = (const float*)d_in[0];
  const float* w1 = (const float*)d_in[1];
  const float* w2 = (const float*)d_in[2];
  const float* wm = (const float*)d_in[3];
  float* out = (float*)d_out;
  u16* mb = (u16*)d_ws;  // M (73,728 B) + wm bf16 (384 B)

  hipLaunchKernelGGL(prep, dim3(CC + 1), dim3(CC), 0, stream, w1, w2, wm, mb);
  hipLaunchKernelGGL(fused, dim3(GRID), dim3(512), LDS_BYTES, stream, x1, mb, out);
}